// Round 3
// baseline (1613.821 us; speedup 1.0000x reference)
//
#include <hip/hip_runtime.h>
#include <hip/hip_bf16.h>

// Transformer-XL relative multi-head attention, MI355X (gfx950).
// Shapes: QLEN=RLEN=KLEN=2048, BSZ=2, NH=16, DH=64, DM=1024. SCALE=0.125.
// Outputs (f32, concat): out0[2048,2,1024], prob[2048,2048,2,16],
//                        AC[2048,2048,2,16], BD[2048,2048,2,16]
// R3: BD fused into stats and prob passes (no BD global re-read; k_bd /
//     k_bdiag removed). Shifted BD assembled per 32-j chunk in LDS from
//     7 aligned RK c-tiles (3 case-1 via Q rows i0.., 4 case-2 via Q rows
//     i0+1..). Non-temporal stores for AC/BD/PROB.

typedef unsigned short u16;
typedef __attribute__((ext_vector_type(8))) short short8;   // 8 bf16 (4 VGPR)
typedef __attribute__((ext_vector_type(4))) float f32x4;
typedef __attribute__((ext_vector_type(4))) unsigned short u16x4;

__device__ __forceinline__ u16 f2bf(float x){
  unsigned u = __float_as_uint(x);
  u += 0x7fffu + ((u >> 16) & 1u);          // RNE
  return (u16)(u >> 16);
}
__device__ __forceinline__ float bf2f(u16 s){
  return __uint_as_float(((unsigned)s) << 16);
}
__device__ __forceinline__ f32x4 mfma16(short8 a, short8 b, f32x4 c){
  return __builtin_amdgcn_mfma_f32_16x16x32_bf16(a, b, c, 0, 0, 0);
}
__device__ __forceinline__ void ntst4(float* p, f32x4 v){
  __builtin_nontemporal_store(v, (f32x4*)p);
}

// ---------------- prep: casts / transposes ----------------

__global__ __launch_bounds__(256) void k_cast(const float* __restrict__ src, u16* __restrict__ dst, int n4){
  int i = blockIdx.x * 256 + threadIdx.x;
  if (i >= n4) return;
  f32x4 v = *(const f32x4*)(src + (size_t)i * 4);
  u16x4 o;
  #pragma unroll
  for (int q = 0; q < 4; ++q) o[q] = f2bf(v[q]);
  *(u16x4*)(dst + (size_t)i * 4) = o;
}

// src f32 [R][C] -> dst bf16 [C][R]
__global__ __launch_bounds__(256) void k_tc(const float* __restrict__ src, u16* __restrict__ dst, int R, int C){
  __shared__ float ld[32][33];
  int c0 = blockIdx.x * 32, r0 = blockIdx.y * 32;
  int t = threadIdx.x;
  int r = t >> 3, c4 = (t & 7) * 4;
  f32x4 v = *(const f32x4*)(src + (size_t)(r0 + r) * C + c0 + c4);
  #pragma unroll
  for (int q = 0; q < 4; ++q) ld[r][c4 + q] = v[q];
  __syncthreads();
  int c = t >> 3, r4 = (t & 7) * 4;
  u16x4 o;
  #pragma unroll
  for (int q = 0; q < 4; ++q) o[q] = f2bf(ld[r4 + q][c]);
  *(u16x4*)(dst + (size_t)(c0 + c) * R + r0 + r4) = o;
}

// ---------------- GEMM: C[M,N] = A[M,1024] @ Bt[N,1024]^T ----------------

template<int MODE>
__global__ __launch_bounds__(512) void k_gemm(const u16* __restrict__ A, const u16* __restrict__ Bt,
        u16* __restrict__ o0, u16* __restrict__ o1, u16* __restrict__ o2,
        const float* __restrict__ wres, float* __restrict__ outf)
{
  __shared__ __align__(16) u16 As[128][40];
  __shared__ __align__(16) u16 Bs[256][40];
  const int t = threadIdx.x;
  const int wave = t >> 6, lane = t & 63;
  const int wr = wave >> 2, wc = wave & 3;
  const int g = lane >> 4, li = lane & 15;
  const int m0 = blockIdx.x * 128, n0 = blockIdx.y * 256;
  f32x4 acc[4][4] = {};
  const int ar = t >> 2, ac8 = (t & 3) * 8;
  for (int kt = 0; kt < 32; ++kt){
    int k0 = kt * 32;
    *(short8*)&As[ar][ac8] = *(const short8*)(A + (size_t)(m0 + ar) * 1024 + k0 + ac8);
    #pragma unroll
    for (int u = 0; u < 2; ++u){
      int id = t + 512 * u; int br = id >> 2, bc8 = (id & 3) * 8;
      *(short8*)&Bs[br][bc8] = *(const short8*)(Bt + (size_t)(n0 + br) * 1024 + k0 + bc8);
    }
    __syncthreads();
    short8 af[4], bfv[4];
    #pragma unroll
    for (int mf = 0; mf < 4; ++mf) af[mf] = *(const short8*)&As[wr * 64 + mf * 16 + li][g * 8];
    #pragma unroll
    for (int nf = 0; nf < 4; ++nf) bfv[nf] = *(const short8*)&Bs[wc * 64 + nf * 16 + li][g * 8];
    #pragma unroll
    for (int mf = 0; mf < 4; ++mf)
      #pragma unroll
      for (int nf = 0; nf < 4; ++nf)
        acc[mf][nf] = mfma16(af[mf], bfv[nf], acc[mf][nf]);
    __syncthreads();
  }
  #pragma unroll
  for (int mf = 0; mf < 4; ++mf)
  #pragma unroll
  for (int nf = 0; nf < 4; ++nf)
  #pragma unroll
  for (int r = 0; r < 4; ++r){
    int gr = m0 + wr * 64 + mf * 16 + g * 4 + r;
    int gc = n0 + wc * 64 + nf * 16 + li;
    float v = acc[mf][nf][r];
    if (MODE == 0){
      int part = gc >> 10, hh = gc & 1023;
      int hn = hh >> 6, d = hh & 63;
      int i = gr >> 1, b = gr & 1;
      u16* dst = (part == 0) ? o0 : ((part == 1) ? o1 : o2);
      dst[((((b << 4) + hn) * 2048 + i) << 6) + d] = f2bf(v);
    } else if (MODE == 1){
      int hn = gc >> 6, d = gc & 63;
      o0[((hn * 2048 + gr) << 6) + d] = f2bf(v);
    } else {
      size_t idx = (size_t)gr * 1024 + gc;
      outf[idx] = wres[idx] + v;
    }
  }
}

// bias vectors: out[g][j] = sum_d bv[g&15][d] * Km[g][j][d]
__global__ __launch_bounds__(256) void k_bias(const u16* __restrict__ Km, const float* __restrict__ bv,
                                              float* __restrict__ out, int total){
  int idx = blockIdx.x * 256 + threadIdx.x;
  if (idx >= total) return;
  int n = (idx >> 11) & 15;
  const u16* kr = Km + ((size_t)idx << 6);
  const float* bp = bv + n * 64;
  float s = 0.f;
  #pragma unroll
  for (int d8 = 0; d8 < 8; ++d8){
    short8 v = *(const short8*)(kr + d8 * 8);
    #pragma unroll
    for (int q = 0; q < 8; ++q) s += bp[d8 * 8 + q] * bf2f((u16)v[q]);
  }
  out[idx] = s;
}

// V [bn][j][d] -> Vt [bn][d][j]
__global__ __launch_bounds__(256) void k_trv(const u16* __restrict__ V, u16* __restrict__ Vt){
  __shared__ __align__(16) u16 ld[64][72];
  int bn = blockIdx.x, j0 = blockIdx.y * 64;
  int t = threadIdx.x;
  #pragma unroll
  for (int u = 0; u < 2; ++u){
    int id = t + 256 * u; int r = id >> 3, c8 = (id & 7) * 8;
    *(short8*)&ld[r][c8] = *(const short8*)(V + ((size_t)(bn * 2048 + j0 + r) << 6) + c8);
  }
  __syncthreads();
  #pragma unroll
  for (int u = 0; u < 2; ++u){
    int id = t + 256 * u; int d = id >> 3, j8 = (id & 7) * 8;
    short8 o;
    #pragma unroll
    for (int q = 0; q < 8; ++q) o[q] = ld[j8 + q][d];
    *(short8*)(Vt + ((size_t)(bn * 64 + d) << 11) + j0 + j8) = o;
  }
}

// ======== fused shifted-BD chunk builder (device inline) ========
// Fills sBD[fr*544 + jw*17 + n] (bf16) for output rows i0..i0+15, j-window
// [j0, j0+32). Caller must have zeroed sBD and barriered. Wave handles
// heads n = wave*2 + {0,1}. qa = Q rows i0..i0+15, qb = Q rows i0+1..i0+16.
__device__ __forceinline__ void bd_scatter(u16* sBD, const u16* __restrict__ RK,
        const float* __restrict__ bias_bd, const short8 qa[2][2], const short8 qb[2][2],
        int m, int wave, int g, int li)
{
  #pragma unroll
  for (int nn = 0; nn < 2; ++nn){
    int n = wave * 2 + nn;
    // case-1 tiles: raw rows i0+fr, c0 = m+2032+16tt, jw = li+fr+16tt-15
    #pragma unroll
    for (int tt = 0; tt < 3; ++tt){
      int c0 = m + 2032 + tt * 16;
      if (c0 < 0 || c0 > 2032) continue;
      const u16* rp = RK + ((size_t)(n * 2048 + c0 + li) << 6) + g * 8;
      short8 b0 = *(const short8*)rp;
      short8 b1 = *(const short8*)(rp + 32);
      f32x4 acc = {};
      acc = mfma16(qa[nn][0], b0, acc);
      acc = mfma16(qa[nn][1], b1, acc);
      float bb = bias_bd[n * 2048 + c0 + li];
      int off = tt * 16 - 15;
      #pragma unroll
      for (int r = 0; r < 4; ++r){
        int fr = g * 4 + r;
        int jw = li + fr + off;
        if ((unsigned)jw < 32u) sBD[fr * 544 + jw * 17 + n] = f2bf(acc[r] + bb);
      }
    }
    // case-2 tiles: raw rows i0+1+fr, c0 = m-32+16tt, jw = li+fr+16tt-30
    #pragma unroll
    for (int tt = 0; tt < 4; ++tt){
      int c0 = m - 32 + tt * 16;
      if (c0 < 0 || c0 > 2032) continue;
      const u16* rp = RK + ((size_t)(n * 2048 + c0 + li) << 6) + g * 8;
      short8 b0 = *(const short8*)rp;
      short8 b1 = *(const short8*)(rp + 32);
      f32x4 acc = {};
      acc = mfma16(qb[nn][0], b0, acc);
      acc = mfma16(qb[nn][1], b1, acc);
      float bb = bias_bd[n * 2048 + c0 + li];
      int off = tt * 16 - 30;
      #pragma unroll
      for (int r = 0; r < 4; ++r){
        int fr = g * 4 + r;
        int jw = li + fr + off;
        if ((unsigned)jw < 32u) sBD[fr * 544 + jw * 17 + n] = f2bf(acc[r] + bb);
      }
    }
  }
}

// ---------------- pass 1: fused BD + AC + split-j softmax stats ----------------
__global__ __launch_bounds__(512, 4) void k_statsF(const u16* __restrict__ Q, const u16* __restrict__ RK,
        const u16* __restrict__ Kc, const float* __restrict__ bias_ac, const float* __restrict__ bias_bd,
        float* __restrict__ ACo, float* __restrict__ BDo,
        float* __restrict__ m_part, float* __restrict__ l_part)
{
  __shared__ __align__(16) u16 sBD[16 * 544];   // [fr][jw][n] strides 544/17
  __shared__ __align__(16) u16 sAC[32 * 271];   // [jl][n*17+row]
  const int t = threadIdx.x, wave = t >> 6, lane = t & 63;
  const int g = lane >> 4, li = lane & 15;
  const int i0 = blockIdx.x * 16, b = blockIdx.y;
  const int jbase = blockIdx.z * 512;
  short8 qa[2][2], qb[2][2];
  #pragma unroll
  for (int nn = 0; nn < 2; ++nn){
    int bn = b * 16 + wave * 2 + nn;
    const u16* qp = Q + ((size_t)(bn * 2048 + i0 + li) << 6) + g * 8;
    qa[nn][0] = *(const short8*)qp;
    qa[nn][1] = *(const short8*)(qp + 32);
    int rowB = i0 + 1 + li; if (rowB > 2047) rowB = 2047;   // row 2048 never used
    const u16* qp2 = Q + ((size_t)(bn * 2048 + rowB) << 6) + g * 8;
    qb[nn][0] = *(const short8*)qp2;
    qb[nn][1] = *(const short8*)(qp2 + 32);
  }
  for (int w = t; w < 4352; w += 512) ((unsigned*)sBD)[w] = 0;

  float m_[2][4], l_[2][4];
  #pragma unroll
  for (int nn = 0; nn < 2; ++nn)
    #pragma unroll
    for (int r = 0; r < 4; ++r){ m_[nn][r] = -__builtin_inff(); l_[nn][r] = 0.f; }

  for (int ch = 0; ch < 16; ++ch){
    int j0 = jbase + ch * 32;
    int m = j0 - i0;
    __syncthreads();                              // zero done / prev flush done
    bd_scatter(sBD, RK, bias_bd, qa, qb, m, wave, g, li);
    __syncthreads();                              // sBD complete
    #pragma unroll
    for (int nn = 0; nn < 2; ++nn){
      int n = wave * 2 + nn, bn = b * 16 + n;
      float sv[2][4];
      #pragma unroll
      for (int cf = 0; cf < 2; ++cf){
        int jc = j0 + cf * 16 + li;
        const u16* kp = Kc + ((size_t)(bn * 2048 + jc) << 6) + g * 8;
        short8 b0 = *(const short8*)kp;
        short8 b1 = *(const short8*)(kp + 32);
        f32x4 acc = {};
        acc = mfma16(qa[nn][0], b0, acc);
        acc = mfma16(qa[nn][1], b1, acc);
        float ba = bias_ac[bn * 2048 + jc];
        #pragma unroll
        for (int r = 0; r < 4; ++r){
          float av = acc[r] + ba;
          sAC[(cf * 16 + li) * 271 + n * 17 + g * 4 + r] = f2bf(av);
          float bd = bf2f(sBD[(g * 4 + r) * 544 + (cf * 16 + li) * 17 + n]);
          sv[cf][r] = (av + bd) * 0.125f;
        }
      }
      float cm[4], mn[4], ps[4];
      #pragma unroll
      for (int r = 0; r < 4; ++r) cm[r] = fmaxf(sv[0][r], sv[1][r]);
      #pragma unroll
      for (int off = 1; off < 16; off <<= 1)
        #pragma unroll
        for (int r = 0; r < 4; ++r) cm[r] = fmaxf(cm[r], __shfl_xor(cm[r], off));
      #pragma unroll
      for (int r = 0; r < 4; ++r){
        mn[r] = fmaxf(m_[nn][r], cm[r]);
        ps[r] = __expf(sv[0][r] - mn[r]) + __expf(sv[1][r] - mn[r]);
      }
      #pragma unroll
      for (int off = 1; off < 16; off <<= 1)
        #pragma unroll
        for (int r = 0; r < 4; ++r) ps[r] += __shfl_xor(ps[r], off);
      #pragma unroll
      for (int r = 0; r < 4; ++r){
        l_[nn][r] = l_[nn][r] * __expf(m_[nn][r] - mn[r]) + ps[r];
        m_[nn][r] = mn[r];
      }
    }
    // BD output flush (reads sBD, complete since barrier)
    #pragma unroll
    for (int u = 0; u < 4; ++u){
      int flat4 = t + 512 * u;
      int n4 = (flat4 & 3) * 4, jl = (flat4 >> 2) & 31, row = flat4 >> 7;
      f32x4 v;
      #pragma unroll
      for (int q = 0; q < 4; ++q) v[q] = bf2f(sBD[row * 544 + jl * 17 + n4 + q]);
      ntst4(BDo + (((size_t)(i0 + row) * 2048 + j0 + jl) << 5) + b * 16 + n4, v);
    }
    __syncthreads();                              // sAC complete, sBD reads done
    // AC flush + zero sBD for next chunk
    #pragma unroll
    for (int u = 0; u < 4; ++u){
      int flat4 = t + 512 * u;
      int n4 = (flat4 & 3) * 4, jl = (flat4 >> 2) & 31, row = flat4 >> 7;
      f32x4 v;
      #pragma unroll
      for (int q = 0; q < 4; ++q) v[q] = bf2f(sAC[jl * 271 + (n4 + q) * 17 + row]);
      ntst4(ACo + (((size_t)(i0 + row) * 2048 + j0 + jl) << 5) + b * 16 + n4, v);
    }
    for (int w = t; w < 4352; w += 512) ((unsigned*)sBD)[w] = 0;
  }
  if (li == 0){
    #pragma unroll
    for (int nn = 0; nn < 2; ++nn)
      #pragma unroll
      for (int r = 0; r < 4; ++r){
        int bn = b * 16 + wave * 2 + nn;
        size_t o = ((size_t)(blockIdx.z * 32 + bn)) * 2048 + i0 + g * 4 + r;
        m_part[o] = m_[nn][r];
        l_part[o] = l_[nn][r];
      }
  }
}

// combine split-j stats: m = max, l = sum l_js * exp(m_js - m)
__global__ __launch_bounds__(256) void k_comb(const float* __restrict__ mp, const float* __restrict__ lp,
                                              float* __restrict__ mf, float* __restrict__ lf){
  int idx = blockIdx.x * 256 + threadIdx.x;    // 32*2048 = 65536
  float m = -__builtin_inff();
  #pragma unroll
  for (int js = 0; js < 4; ++js) m = fmaxf(m, mp[js * 65536 + idx]);
  float l = 0.f;
  #pragma unroll
  for (int js = 0; js < 4; ++js) l += lp[js * 65536 + idx] * __expf(mp[js * 65536 + idx] - m);
  mf[idx] = m;
  lf[idx] = l;
}

// ---------------- pass 2: fused BD + AC + prob write + P.V partials ----------------
__global__ __launch_bounds__(512, 4) void k_probF(const u16* __restrict__ Q, const u16* __restrict__ RK,
        const u16* __restrict__ Kc, const u16* __restrict__ Vt,
        const float* __restrict__ bias_ac, const float* __restrict__ bias_bd,
        const float* __restrict__ m_f, const float* __restrict__ l_f,
        float* __restrict__ PROB, float* __restrict__ Ovp)
{
  __shared__ __align__(16) u16 sBD[16 * 544];
  __shared__ __align__(16) u16 sP[32 * 271];
  const int t = threadIdx.x, wave = t >> 6, lane = t & 63;
  const int g = lane >> 4, li = lane & 15;
  const int i0 = blockIdx.x * 16, b = blockIdx.y;
  const int jbase = blockIdx.z * 512;
  short8 qa[2][2];
  float m_[2][4], rl_[2][4];
  #pragma unroll
  for (int nn = 0; nn < 2; ++nn){
    int bn = b * 16 + wave * 2 + nn;
    const u16* qp = Q + ((size_t)(bn * 2048 + i0 + li) << 6) + g * 8;
    qa[nn][0] = *(const short8*)qp;
    qa[nn][1] = *(const short8*)(qp + 32);
    #pragma unroll
    for (int r = 0; r < 4; ++r){
      m_[nn][r]  = m_f[bn * 2048 + i0 + g * 4 + r];
      rl_[nn][r] = 1.f / l_f[bn * 2048 + i0 + g * 4 + r];
    }
  }
  for (int w = t; w < 4352; w += 512) ((unsigned*)sBD)[w] = 0;
  f32x4 oacc[2][4] = {};

  for (int ch = 0; ch < 16; ++ch){
    int j0 = jbase + ch * 32;
    int m = j0 - i0;
    __syncthreads();
    {
      // qb loaded transiently to limit VGPR pressure
      short8 qb[2][2];
      #pragma unroll
      for (int nn = 0; nn < 2; ++nn){
        int bn = b * 16 + wave * 2 + nn;
        int rowB = i0 + 1 + li; if (rowB > 2047) rowB = 2047;
        const u16* qp2 = Q + ((size_t)(bn * 2048 + rowB) << 6) + g * 8;
        qb[nn][0] = *(const short8*)qp2;
        qb[nn][1] = *(const short8*)(qp2 + 32);
      }
      bd_scatter(sBD, RK, bias_bd, qa, qb, m, wave, g, li);
    }
    __syncthreads();
    #pragma unroll
    for (int nn = 0; nn < 2; ++nn){
      int n = wave * 2 + nn, bn = b * 16 + n;
      #pragma unroll
      for (int cf = 0; cf < 2; ++cf){
        int jc = j0 + cf * 16 + li;
        const u16* kp = Kc + ((size_t)(bn * 2048 + jc) << 6) + g * 8;
        short8 b0 = *(const short8*)kp;
        short8 b1 = *(const short8*)(kp + 32);
        f32x4 acc = {};
        acc = mfma16(qa[nn][0], b0, acc);
        acc = mfma16(qa[nn][1], b1, acc);
        float ba = bias_ac[bn * 2048 + jc];
        #pragma unroll
        for (int r = 0; r < 4; ++r){
          float bd = bf2f(sBD[(g * 4 + r) * 544 + (cf * 16 + li) * 17 + n]);
          float s = (acc[r] + ba + bd) * 0.125f;
          float p = __expf(s - m_[nn][r]) * rl_[nn][r];
          sP[(cf * 16 + li) * 271 + n * 17 + g * 4 + r] = f2bf(p);
        }
      }
    }
    // PV: own-wave repack from sP (A-frag: row=lane&15, k=8*(lane>>4)+tt)
    #pragma unroll
    for (int nn = 0; nn < 2; ++nn){
      int n = wave * 2 + nn, bn = b * 16 + n;
      short8 pa;
      #pragma unroll
      for (int tt = 0; tt < 8; ++tt) pa[tt] = (short)sP[(g * 8 + tt) * 271 + n * 17 + li];
      const u16* vb = Vt + ((size_t)(bn * 64) << 11) + j0 + g * 8;
      #pragma unroll
      for (int vf = 0; vf < 4; ++vf){
        short8 bv = *(const short8*)(vb + ((size_t)(vf * 16 + li) << 11));
        oacc[nn][vf] = mfma16(pa, bv, oacc[nn][vf]);
      }
    }
    __syncthreads();
    #pragma unroll
    for (int u = 0; u < 4; ++u){
      int flat4 = t + 512 * u;
      int n4 = (flat4 & 3) * 4, jl = (flat4 >> 2) & 31, row = flat4 >> 7;
      f32x4 v;
      #pragma unroll
      for (int q = 0; q < 4; ++q) v[q] = bf2f(sP[jl * 271 + (n4 + q) * 17 + row]);
      ntst4(PROB + (((size_t)(i0 + row) * 2048 + j0 + jl) << 5) + b * 16 + n4, v);
    }
    for (int w = t; w < 4352; w += 512) ((unsigned*)sBD)[w] = 0;
  }
  float* op = Ovp + (size_t)blockIdx.z * 4194304;
  #pragma unroll
  for (int nn = 0; nn < 2; ++nn){
    int n = wave * 2 + nn;
    #pragma unroll
    for (int vf = 0; vf < 4; ++vf)
      #pragma unroll
      for (int r = 0; r < 4; ++r)
        op[(size_t)((i0 + g * 4 + r) * 2 + b) * 1024 + n * 64 + vf * 16 + li] = oacc[nn][vf][r];
  }
}

// reduce 4 PV partials -> bf16 attn_vec
__global__ __launch_bounds__(256) void k_ovred(const float* __restrict__ ovp, u16* __restrict__ ov){
  int i = blockIdx.x * 256 + threadIdx.x;      // over 1048576 f32x4 groups
  const f32x4* p = (const f32x4*)ovp;
  f32x4 s = p[i];
  #pragma unroll
  for (int js = 1; js < 4; ++js) s += p[(size_t)js * 1048576 + i];
  u16x4 o;
  #pragma unroll
  for (int q = 0; q < 4; ++q) o[q] = f2bf(s[q]);
  ((u16x4*)ov)[i] = o;
}

// ---------------- launch ----------------

extern "C" void kernel_launch(void* const* d_in, const int* in_sizes, int n_in,
                              void* d_out, int out_size, void* d_ws, size_t ws_size,
                              hipStream_t stream)
{
  const float* w      = (const float*)d_in[0];
  const float* r      = (const float*)d_in[1];
  const float* qkv_w  = (const float*)d_in[2];
  const float* rnet_w = (const float*)d_in[3];
  const float* o_w    = (const float*)d_in[4];
  const float* rrb    = (const float*)d_in[5];  // r_r_bias -> BD
  const float* rwb    = (const float*)d_in[6];  // r_w_bias -> AC

  char* ws = (char*)d_ws;
  size_t off = 0;
  auto alloc = [&](size_t bytes) -> void* {
    void* p = ws + off; off += (bytes + 255) & ~(size_t)255; return p;
  };
  u16* Xbf    = (u16*)alloc((size_t)4096 * 1024 * 2);
  u16* Rbf    = (u16*)alloc((size_t)2048 * 1024 * 2);
  u16* Wqkvt  = (u16*)alloc((size_t)3072 * 1024 * 2);
  u16* Wrt    = (u16*)alloc((size_t)1024 * 1024 * 2);
  u16* Wot    = (u16*)alloc((size_t)1024 * 1024 * 2);
  u16* Qs     = (u16*)alloc((size_t)32 * 2048 * 64 * 2);
  u16* Ks     = (u16*)alloc((size_t)32 * 2048 * 64 * 2);
  u16* Vs     = (u16*)alloc((size_t)32 * 2048 * 64 * 2);
  u16* Vts    = (u16*)alloc((size_t)32 * 64 * 2048 * 2);
  u16* RKs    = (u16*)alloc((size_t)16 * 2048 * 64 * 2);
  float* bias_ac = (float*)alloc((size_t)32 * 2048 * 4);
  float* bias_bd = (float*)alloc((size_t)16 * 2048 * 4);
  float* m_part  = (float*)alloc((size_t)4 * 32 * 2048 * 4);
  float* l_part  = (float*)alloc((size_t)4 * 32 * 2048 * 4);
  float* m_fin   = (float*)alloc((size_t)32 * 2048 * 4);
  float* l_fin   = (float*)alloc((size_t)32 * 2048 * 4);
  float* Ovp     = (float*)alloc((size_t)4 * 4096 * 1024 * 4);
  u16* Ov     = (u16*)alloc((size_t)4096 * 1024 * 2);

  float* out0 = (float*)d_out;
  float* PROB = out0 + 4194304;
  float* ACo  = PROB + 134217728;
  float* BDo  = ACo  + 134217728;

  k_cast<<<dim3(4096), dim3(256), 0, stream>>>(w, Xbf, 1048576);
  k_cast<<<dim3(2048), dim3(256), 0, stream>>>(r, Rbf, 524288);
  k_tc<<<dim3(96, 32), dim3(256), 0, stream>>>(qkv_w,  Wqkvt, 1024, 3072);
  k_tc<<<dim3(32, 32), dim3(256), 0, stream>>>(rnet_w, Wrt,   1024, 1024);
  k_tc<<<dim3(32, 32), dim3(256), 0, stream>>>(o_w,    Wot,   1024, 1024);
  k_gemm<0><<<dim3(32, 12), dim3(512), 0, stream>>>(Xbf, Wqkvt, Qs, Ks, Vs, nullptr, nullptr);
  k_gemm<1><<<dim3(16, 4),  dim3(512), 0, stream>>>(Rbf, Wrt,  RKs, nullptr, nullptr, nullptr, nullptr);
  k_bias<<<dim3(256), dim3(256), 0, stream>>>(Ks,  rwb, bias_ac, 65536);
  k_bias<<<dim3(128), dim3(256), 0, stream>>>(RKs, rrb, bias_bd, 32768);
  k_trv<<<dim3(32, 32), dim3(256), 0, stream>>>(Vs, Vts);
  k_statsF<<<dim3(128, 2, 4), dim3(512), 0, stream>>>(Qs, RKs, Ks, bias_ac, bias_bd, ACo, BDo, m_part, l_part);
  k_comb<<<dim3(256), dim3(256), 0, stream>>>(m_part, l_part, m_fin, l_fin);
  k_probF<<<dim3(128, 2, 4), dim3(512), 0, stream>>>(Qs, RKs, Ks, Vts, bias_ac, bias_bd, m_fin, l_fin, PROB, Ovp);
  k_ovred<<<dim3(4096), dim3(256), 0, stream>>>(Ovp, Ov);
  k_gemm<2><<<dim3(32, 4), dim3(512), 0, stream>>>(Ov, Wot, nullptr, nullptr, nullptr, w, out0);
}

// Round 4
// 1257.022 us; speedup vs baseline: 1.2838x; 1.2838x over previous
//
#include <hip/hip_runtime.h>
#include <hip/hip_bf16.h>

// Transformer-XL relative multi-head attention, MI355X (gfx950).
// Shapes: QLEN=RLEN=KLEN=2048, BSZ=2, NH=16, DH=64, DM=1024. SCALE=0.125.
// Outputs (f32, concat): out0[2048,2,1024], prob[2048,2048,2,16],
//                        AC[2048,2048,2,16], BD[2048,2048,2,16]
// R4: revert R3 fusion (was +240us of redundant BD MFMA). R2 structure +
//     (a) register-prefetch of next BD chunk overlapped with compute,
//     (b) bf16 LDS staging of BD (lossless: BD values are bf16-rounded),
//     (c) non-temporal stores for BD/AC/PROB.

typedef unsigned short u16;
typedef __attribute__((ext_vector_type(8))) short short8;   // 8 bf16 (4 VGPR)
typedef __attribute__((ext_vector_type(4))) float f32x4;
typedef __attribute__((ext_vector_type(4))) unsigned short u16x4;

__device__ __forceinline__ u16 f2bf(float x){
  unsigned u = __float_as_uint(x);
  u += 0x7fffu + ((u >> 16) & 1u);          // RNE
  return (u16)(u >> 16);
}
__device__ __forceinline__ float bf2f(u16 s){
  return __uint_as_float(((unsigned)s) << 16);
}
__device__ __forceinline__ f32x4 mfma16(short8 a, short8 b, f32x4 c){
  return __builtin_amdgcn_mfma_f32_16x16x32_bf16(a, b, c, 0, 0, 0);
}
__device__ __forceinline__ void ntst4(float* p, f32x4 v){
  __builtin_nontemporal_store(v, (f32x4*)p);
}

// ---------------- prep: casts / transposes ----------------

__global__ __launch_bounds__(256) void k_cast(const float* __restrict__ src, u16* __restrict__ dst, int n4){
  int i = blockIdx.x * 256 + threadIdx.x;
  if (i >= n4) return;
  f32x4 v = *(const f32x4*)(src + (size_t)i * 4);
  u16x4 o;
  #pragma unroll
  for (int q = 0; q < 4; ++q) o[q] = f2bf(v[q]);
  *(u16x4*)(dst + (size_t)i * 4) = o;
}

// src f32 [R][C] -> dst bf16 [C][R]
__global__ __launch_bounds__(256) void k_tc(const float* __restrict__ src, u16* __restrict__ dst, int R, int C){
  __shared__ float ld[32][33];
  int c0 = blockIdx.x * 32, r0 = blockIdx.y * 32;
  int t = threadIdx.x;
  int r = t >> 3, c4 = (t & 7) * 4;
  f32x4 v = *(const f32x4*)(src + (size_t)(r0 + r) * C + c0 + c4);
  #pragma unroll
  for (int q = 0; q < 4; ++q) ld[r][c4 + q] = v[q];
  __syncthreads();
  int c = t >> 3, r4 = (t & 7) * 4;
  u16x4 o;
  #pragma unroll
  for (int q = 0; q < 4; ++q) o[q] = f2bf(ld[r4 + q][c]);
  *(u16x4*)(dst + (size_t)(c0 + c) * R + r0 + r4) = o;
}

// ---------------- GEMM: C[M,N] = A[M,1024] @ Bt[N,1024]^T ----------------

template<int MODE>
__global__ __launch_bounds__(512) void k_gemm(const u16* __restrict__ A, const u16* __restrict__ Bt,
        u16* __restrict__ o0, u16* __restrict__ o1, u16* __restrict__ o2,
        const float* __restrict__ wres, float* __restrict__ outf)
{
  __shared__ __align__(16) u16 As[128][40];
  __shared__ __align__(16) u16 Bs[256][40];
  const int t = threadIdx.x;
  const int wave = t >> 6, lane = t & 63;
  const int wr = wave >> 2, wc = wave & 3;
  const int g = lane >> 4, li = lane & 15;
  const int m0 = blockIdx.x * 128, n0 = blockIdx.y * 256;
  f32x4 acc[4][4] = {};
  const int ar = t >> 2, ac8 = (t & 3) * 8;
  for (int kt = 0; kt < 32; ++kt){
    int k0 = kt * 32;
    *(short8*)&As[ar][ac8] = *(const short8*)(A + (size_t)(m0 + ar) * 1024 + k0 + ac8);
    #pragma unroll
    for (int u = 0; u < 2; ++u){
      int id = t + 512 * u; int br = id >> 2, bc8 = (id & 3) * 8;
      *(short8*)&Bs[br][bc8] = *(const short8*)(Bt + (size_t)(n0 + br) * 1024 + k0 + bc8);
    }
    __syncthreads();
    short8 af[4], bfv[4];
    #pragma unroll
    for (int mf = 0; mf < 4; ++mf) af[mf] = *(const short8*)&As[wr * 64 + mf * 16 + li][g * 8];
    #pragma unroll
    for (int nf = 0; nf < 4; ++nf) bfv[nf] = *(const short8*)&Bs[wc * 64 + nf * 16 + li][g * 8];
    #pragma unroll
    for (int mf = 0; mf < 4; ++mf)
      #pragma unroll
      for (int nf = 0; nf < 4; ++nf)
        acc[mf][nf] = mfma16(af[mf], bfv[nf], acc[mf][nf]);
    __syncthreads();
  }
  #pragma unroll
  for (int mf = 0; mf < 4; ++mf)
  #pragma unroll
  for (int nf = 0; nf < 4; ++nf)
  #pragma unroll
  for (int r = 0; r < 4; ++r){
    int gr = m0 + wr * 64 + mf * 16 + g * 4 + r;
    int gc = n0 + wc * 64 + nf * 16 + li;
    float v = acc[mf][nf][r];
    if (MODE == 0){
      int part = gc >> 10, hh = gc & 1023;
      int hn = hh >> 6, d = hh & 63;
      int i = gr >> 1, b = gr & 1;
      u16* dst = (part == 0) ? o0 : ((part == 1) ? o1 : o2);
      dst[((((b << 4) + hn) * 2048 + i) << 6) + d] = f2bf(v);
    } else if (MODE == 1){
      int hn = gc >> 6, d = gc & 63;
      o0[((hn * 2048 + gr) << 6) + d] = f2bf(v);
    } else {
      size_t idx = (size_t)gr * 1024 + gc;
      outf[idx] = wres[idx] + v;
    }
  }
}

// bias vectors: out[g][j] = sum_d bv[g&15][d] * Km[g][j][d]
__global__ __launch_bounds__(256) void k_bias(const u16* __restrict__ Km, const float* __restrict__ bv,
                                              float* __restrict__ out, int total){
  int idx = blockIdx.x * 256 + threadIdx.x;
  if (idx >= total) return;
  int n = (idx >> 11) & 15;
  const u16* kr = Km + ((size_t)idx << 6);
  const float* bp = bv + n * 64;
  float s = 0.f;
  #pragma unroll
  for (int d8 = 0; d8 < 8; ++d8){
    short8 v = *(const short8*)(kr + d8 * 8);
    #pragma unroll
    for (int q = 0; q < 8; ++q) s += bp[d8 * 8 + q] * bf2f((u16)v[q]);
  }
  out[idx] = s;
}

// V [bn][j][d] -> Vt [bn][d][j]
__global__ __launch_bounds__(256) void k_trv(const u16* __restrict__ V, u16* __restrict__ Vt){
  __shared__ __align__(16) u16 ld[64][72];
  int bn = blockIdx.x, j0 = blockIdx.y * 64;
  int t = threadIdx.x;
  #pragma unroll
  for (int u = 0; u < 2; ++u){
    int id = t + 256 * u; int r = id >> 3, c8 = (id & 7) * 8;
    *(short8*)&ld[r][c8] = *(const short8*)(V + ((size_t)(bn * 2048 + j0 + r) << 6) + c8);
  }
  __syncthreads();
  #pragma unroll
  for (int u = 0; u < 2; ++u){
    int id = t + 256 * u; int d = id >> 3, j8 = (id & 7) * 8;
    short8 o;
    #pragma unroll
    for (int q = 0; q < 8; ++q) o[q] = ld[j8 + q][d];
    *(short8*)(Vt + ((size_t)(bn * 64 + d) << 11) + j0 + j8) = o;
  }
}

// ---------------- BD: raw = Q.RK^T + bias_bd, written rel-shifted ----------------
// raw[i',c] -> BD[i', c+i'-2047] if c>=2047-i'  else BD[i'-1, c+i'+1] (skip i'==0)
__global__ __launch_bounds__(512, 4) void k_bd(const u16* __restrict__ Q, const u16* __restrict__ RK,
        const float* __restrict__ bias_bd, float* __restrict__ BD)
{
  __shared__ u16 Cs[32 * 271];                 // [c][n*17+row], odd strides
  const int t = threadIdx.x, wave = t >> 6, lane = t & 63;
  const int g = lane >> 4, li = lane & 15;
  const int i0 = blockIdx.x * 16, b = blockIdx.y;
  const int cbase = blockIdx.z * 512;
  short8 qa[2][2];
  #pragma unroll
  for (int nn = 0; nn < 2; ++nn){
    int bn = b * 16 + wave * 2 + nn;
    const u16* qp = Q + ((size_t)(bn * 2048 + i0 + li) << 6) + g * 8;
    qa[nn][0] = *(const short8*)qp;
    qa[nn][1] = *(const short8*)(qp + 32);
  }
  for (int ch = 0; ch < 16; ++ch){
    int c0 = cbase + ch * 32;
    #pragma unroll
    for (int nn = 0; nn < 2; ++nn){
      int n = wave * 2 + nn;
      #pragma unroll
      for (int cf = 0; cf < 2; ++cf){
        int ccol = c0 + cf * 16 + li;
        const u16* rp = RK + ((size_t)(n * 2048 + ccol) << 6) + g * 8;
        short8 b0 = *(const short8*)rp;
        short8 b1 = *(const short8*)(rp + 32);
        f32x4 acc = {};
        acc = mfma16(qa[nn][0], b0, acc);
        acc = mfma16(qa[nn][1], b1, acc);
        float bb = bias_bd[n * 2048 + ccol];
        #pragma unroll
        for (int r = 0; r < 4; ++r)
          Cs[(cf * 16 + li) * 271 + n * 17 + g * 4 + r] = f2bf(acc[r] + bb);
      }
    }
    __syncthreads();
    #pragma unroll
    for (int u = 0; u < 4; ++u){
      int flat4 = t + 512 * u;                 // 2048 float4 units: [row][c][n4]
      int n4 = (flat4 & 3) * 4, cl = (flat4 >> 2) & 31, row = flat4 >> 7;
      int ip = i0 + row, cg = c0 + cl;
      bool p1 = (cg >= 2047 - ip);
      int ro = p1 ? ip : (ip - 1);
      int j  = cg + (p1 ? (ip - 2047) : (ip + 1));
      if (ro >= 0){
        f32x4 v;
        #pragma unroll
        for (int q = 0; q < 4; ++q) v[q] = bf2f(Cs[cl * 271 + (n4 + q) * 17 + row]);
        ntst4(BD + (((size_t)ro * 2048 + j) << 5) + b * 16 + n4, v);
      }
    }
    __syncthreads();
  }
}

__global__ __launch_bounds__(256) void k_bdiag(float* __restrict__ BD){
  int idx = blockIdx.x * 256 + threadIdx.x;    // i in [0,2047), 32 lanes of (b,n)
  int i = idx >> 5, c = idx & 31;
  if (i < 2047) BD[(((size_t)i * 2048 + i + 1) << 5) + c] = 0.f;
}

// ---------------- pass 1: AC = Q.K^T + bias_ac (write), split-j softmax stats ----------------
// BD staged in LDS as bf16 (lossless: BD was bf16-rounded), strides 648/20
// for 8B-aligned conflict-free access. Next chunk prefetched to regs during
// compute.
__global__ __launch_bounds__(512, 4) void k_stats(const u16* __restrict__ Q, const u16* __restrict__ Kc,
        const float* __restrict__ bias_ac, const float* __restrict__ BD,
        float* __restrict__ ACo, float* __restrict__ m_part, float* __restrict__ l_part)
{
  __shared__ __align__(16) u16 sA[16 * 648];   // BD in: [row]*648 + [j]*20 + n
  __shared__ u16 sB[32 * 271];                 // AC out: [j]*271 + n*17 + row
  const int t = threadIdx.x, wave = t >> 6, lane = t & 63;
  const int g = lane >> 4, li = lane & 15;
  const int i0 = blockIdx.x * 16, b = blockIdx.y;
  const int jbase = blockIdx.z * 512;
  short8 qa[2][2];
  #pragma unroll
  for (int nn = 0; nn < 2; ++nn){
    int bn = b * 16 + wave * 2 + nn;
    const u16* qp = Q + ((size_t)(bn * 2048 + i0 + li) << 6) + g * 8;
    qa[nn][0] = *(const short8*)qp;
    qa[nn][1] = *(const short8*)(qp + 32);
  }
  float m_[2][4], l_[2][4];
  #pragma unroll
  for (int nn = 0; nn < 2; ++nn)
    #pragma unroll
    for (int r = 0; r < 4; ++r){ m_[nn][r] = -__builtin_inff(); l_[nn][r] = 0.f; }

  f32x4 pfv[4];
  #pragma unroll
  for (int u = 0; u < 4; ++u){
    int flat4 = t + 512 * u;
    int n4 = (flat4 & 3) * 4, jl = (flat4 >> 2) & 31, row = flat4 >> 7;
    pfv[u] = *(const f32x4*)(BD + (((size_t)(i0 + row) * 2048 + jbase + jl) << 5) + b * 16 + n4);
  }

  for (int ch = 0; ch < 16; ++ch){
    int j0 = jbase + ch * 32;
    __syncthreads();                           // prev compute/flush done with LDS
    #pragma unroll
    for (int u = 0; u < 4; ++u){               // stage prefetched BD as bf16
      int flat4 = t + 512 * u;
      int n4 = (flat4 & 3) * 4, jl = (flat4 >> 2) & 31, row = flat4 >> 7;
      u16x4 o;
      #pragma unroll
      for (int q = 0; q < 4; ++q) o[q] = (u16)(__float_as_uint(pfv[u][q]) >> 16);
      *(u16x4*)&sA[row * 648 + jl * 20 + n4] = o;
    }
    if (ch + 1 < 16){                          // issue next-chunk loads (overlap compute)
      #pragma unroll
      for (int u = 0; u < 4; ++u){
        int flat4 = t + 512 * u;
        int n4 = (flat4 & 3) * 4, jl = (flat4 >> 2) & 31, row = flat4 >> 7;
        pfv[u] = *(const f32x4*)(BD + (((size_t)(i0 + row) * 2048 + j0 + 32 + jl) << 5) + b * 16 + n4);
      }
    }
    __syncthreads();                           // sA ready
    #pragma unroll
    for (int nn = 0; nn < 2; ++nn){
      int n = wave * 2 + nn, bn = b * 16 + n;
      float sv[2][4];
      #pragma unroll
      for (int cf = 0; cf < 2; ++cf){
        int jc = j0 + cf * 16 + li;
        const u16* kp = Kc + ((size_t)(bn * 2048 + jc) << 6) + g * 8;
        short8 b0 = *(const short8*)kp;
        short8 b1 = *(const short8*)(kp + 32);
        f32x4 acc = {};
        acc = mfma16(qa[nn][0], b0, acc);
        acc = mfma16(qa[nn][1], b1, acc);
        float ba = bias_ac[bn * 2048 + jc];
        #pragma unroll
        for (int r = 0; r < 4; ++r){
          float av = acc[r] + ba;                               // AC value
          sB[(cf * 16 + li) * 271 + n * 17 + g * 4 + r] = f2bf(av);
          float bd = bf2f(sA[(g * 4 + r) * 648 + (cf * 16 + li) * 20 + n]);
          sv[cf][r] = (av + bd) * 0.125f;
        }
      }
      float cm[4], mn[4], ps[4];
      #pragma unroll
      for (int r = 0; r < 4; ++r) cm[r] = fmaxf(sv[0][r], sv[1][r]);
      #pragma unroll
      for (int off = 1; off < 16; off <<= 1)
        #pragma unroll
        for (int r = 0; r < 4; ++r) cm[r] = fmaxf(cm[r], __shfl_xor(cm[r], off));
      #pragma unroll
      for (int r = 0; r < 4; ++r){
        mn[r] = fmaxf(m_[nn][r], cm[r]);
        ps[r] = __expf(sv[0][r] - mn[r]) + __expf(sv[1][r] - mn[r]);
      }
      #pragma unroll
      for (int off = 1; off < 16; off <<= 1)
        #pragma unroll
        for (int r = 0; r < 4; ++r) ps[r] += __shfl_xor(ps[r], off);
      #pragma unroll
      for (int r = 0; r < 4; ++r){
        l_[nn][r] = l_[nn][r] * __expf(m_[nn][r] - mn[r]) + ps[r];
        m_[nn][r] = mn[r];
      }
    }
    __syncthreads();                           // sB complete
    #pragma unroll
    for (int u = 0; u < 4; ++u){
      int flat4 = t + 512 * u;
      int n4 = (flat4 & 3) * 4, jl = (flat4 >> 2) & 31, row = flat4 >> 7;
      f32x4 v;
      #pragma unroll
      for (int q = 0; q < 4; ++q) v[q] = bf2f(sB[jl * 271 + (n4 + q) * 17 + row]);
      ntst4(ACo + (((size_t)(i0 + row) * 2048 + j0 + jl) << 5) + b * 16 + n4, v);
    }
  }
  if (li == 0){
    #pragma unroll
    for (int nn = 0; nn < 2; ++nn)
      #pragma unroll
      for (int r = 0; r < 4; ++r){
        int bn = b * 16 + wave * 2 + nn;
        size_t o = ((size_t)(blockIdx.z * 32 + bn)) * 2048 + i0 + g * 4 + r;
        m_part[o] = m_[nn][r];
        l_part[o] = l_[nn][r];
      }
  }
}

// combine split-j stats: m = max, l = sum l_js * exp(m_js - m)
__global__ __launch_bounds__(256) void k_comb(const float* __restrict__ mp, const float* __restrict__ lp,
                                              float* __restrict__ mf, float* __restrict__ lf){
  int idx = blockIdx.x * 256 + threadIdx.x;    // 32*2048 = 65536
  float m = -__builtin_inff();
  #pragma unroll
  for (int js = 0; js < 4; ++js) m = fmaxf(m, mp[js * 65536 + idx]);
  float l = 0.f;
  #pragma unroll
  for (int js = 0; js < 4; ++js) l += lp[js * 65536 + idx] * __expf(mp[js * 65536 + idx] - m);
  mf[idx] = m;
  lf[idx] = l;
}

// ---------------- pass 2: prob write + P.V partials ----------------
__global__ __launch_bounds__(512, 4) void k_prob_pv(const u16* __restrict__ Q, const u16* __restrict__ Kc,
        const u16* __restrict__ Vt, const float* __restrict__ bias_ac, const float* __restrict__ BD,
        const float* __restrict__ m_f, const float* __restrict__ l_f,
        float* __restrict__ PROB, float* __restrict__ Ovp)
{
  __shared__ __align__(16) u16 sA[16 * 648];
  __shared__ u16 sB[32 * 271];
  const int t = threadIdx.x, wave = t >> 6, lane = t & 63;
  const int g = lane >> 4, li = lane & 15;
  const int i0 = blockIdx.x * 16, b = blockIdx.y;
  const int jbase = blockIdx.z * 512;
  short8 qa[2][2];
  float m_[2][4], rl_[2][4];
  #pragma unroll
  for (int nn = 0; nn < 2; ++nn){
    int bn = b * 16 + wave * 2 + nn;
    const u16* qp = Q + ((size_t)(bn * 2048 + i0 + li) << 6) + g * 8;
    qa[nn][0] = *(const short8*)qp;
    qa[nn][1] = *(const short8*)(qp + 32);
    #pragma unroll
    for (int r = 0; r < 4; ++r){
      m_[nn][r]  = m_f[bn * 2048 + i0 + g * 4 + r];
      rl_[nn][r] = 1.f / l_f[bn * 2048 + i0 + g * 4 + r];
    }
  }
  f32x4 oacc[2][4] = {};

  f32x4 pfv[4];
  #pragma unroll
  for (int u = 0; u < 4; ++u){
    int flat4 = t + 512 * u;
    int n4 = (flat4 & 3) * 4, jl = (flat4 >> 2) & 31, row = flat4 >> 7;
    pfv[u] = *(const f32x4*)(BD + (((size_t)(i0 + row) * 2048 + jbase + jl) << 5) + b * 16 + n4);
  }

  for (int ch = 0; ch < 16; ++ch){
    int j0 = jbase + ch * 32;
    __syncthreads();
    #pragma unroll
    for (int u = 0; u < 4; ++u){
      int flat4 = t + 512 * u;
      int n4 = (flat4 & 3) * 4, jl = (flat4 >> 2) & 31, row = flat4 >> 7;
      u16x4 o;
      #pragma unroll
      for (int q = 0; q < 4; ++q) o[q] = (u16)(__float_as_uint(pfv[u][q]) >> 16);
      *(u16x4*)&sA[row * 648 + jl * 20 + n4] = o;
    }
    if (ch + 1 < 16){
      #pragma unroll
      for (int u = 0; u < 4; ++u){
        int flat4 = t + 512 * u;
        int n4 = (flat4 & 3) * 4, jl = (flat4 >> 2) & 31, row = flat4 >> 7;
        pfv[u] = *(const f32x4*)(BD + (((size_t)(i0 + row) * 2048 + j0 + 32 + jl) << 5) + b * 16 + n4);
      }
    }
    __syncthreads();
    #pragma unroll
    for (int nn = 0; nn < 2; ++nn){
      int n = wave * 2 + nn, bn = b * 16 + n;
      #pragma unroll
      for (int cf = 0; cf < 2; ++cf){
        int jc = j0 + cf * 16 + li;
        const u16* kp = Kc + ((size_t)(bn * 2048 + jc) << 6) + g * 8;
        short8 b0 = *(const short8*)kp;
        short8 b1 = *(const short8*)(kp + 32);
        f32x4 acc = {};
        acc = mfma16(qa[nn][0], b0, acc);
        acc = mfma16(qa[nn][1], b1, acc);
        float ba = bias_ac[bn * 2048 + jc];
        #pragma unroll
        for (int r = 0; r < 4; ++r){
          float bd = bf2f(sA[(g * 4 + r) * 648 + (cf * 16 + li) * 20 + n]);
          float s = (acc[r] + ba + bd) * 0.125f;
          float p = __expf(s - m_[nn][r]) * rl_[nn][r];
          sB[(cf * 16 + li) * 271 + n * 17 + g * 4 + r] = f2bf(p);
        }
      }
    }
    // PV: own-wave repack from sB (A-frag: row=lane&15, k=8*(lane>>4)+tt)
    #pragma unroll
    for (int nn = 0; nn < 2; ++nn){
      int n = wave * 2 + nn, bn = b * 16 + n;
      short8 pa;
      #pragma unroll
      for (int tt = 0; tt < 8; ++tt) pa[tt] = (short)sB[(g * 8 + tt) * 271 + n * 17 + li];
      const u16* vb = Vt + ((size_t)(bn * 64) << 11) + j0 + g * 8;
      #pragma unroll
      for (int vf = 0; vf < 4; ++vf){
        short8 bv = *(const short8*)(vb + ((size_t)(vf * 16 + li) << 11));
        oacc[nn][vf] = mfma16(pa, bv, oacc[nn][vf]);
      }
    }
    __syncthreads();
    #pragma unroll
    for (int u = 0; u < 4; ++u){
      int flat4 = t + 512 * u;
      int n4 = (flat4 & 3) * 4, jl = (flat4 >> 2) & 31, row = flat4 >> 7;
      f32x4 v;
      #pragma unroll
      for (int q = 0; q < 4; ++q) v[q] = bf2f(sB[jl * 271 + (n4 + q) * 17 + row]);
      ntst4(PROB + (((size_t)(i0 + row) * 2048 + j0 + jl) << 5) + b * 16 + n4, v);
    }
  }
  float* op = Ovp + (size_t)blockIdx.z * 4194304;
  #pragma unroll
  for (int nn = 0; nn < 2; ++nn){
    int n = wave * 2 + nn;
    #pragma unroll
    for (int vf = 0; vf < 4; ++vf)
      #pragma unroll
      for (int r = 0; r < 4; ++r)
        op[(size_t)((i0 + g * 4 + r) * 2 + b) * 1024 + n * 64 + vf * 16 + li] = oacc[nn][vf][r];
  }
}

// reduce 4 PV partials -> bf16 attn_vec
__global__ __launch_bounds__(256) void k_ovred(const float* __restrict__ ovp, u16* __restrict__ ov){
  int i = blockIdx.x * 256 + threadIdx.x;      // over 1048576 f32x4 groups
  const f32x4* p = (const f32x4*)ovp;
  f32x4 s = p[i];
  #pragma unroll
  for (int js = 1; js < 4; ++js) s += p[(size_t)js * 1048576 + i];
  u16x4 o;
  #pragma unroll
  for (int q = 0; q < 4; ++q) o[q] = f2bf(s[q]);
  ((u16x4*)ov)[i] = o;
}

// ---------------- launch ----------------

extern "C" void kernel_launch(void* const* d_in, const int* in_sizes, int n_in,
                              void* d_out, int out_size, void* d_ws, size_t ws_size,
                              hipStream_t stream)
{
  const float* w      = (const float*)d_in[0];
  const float* r      = (const float*)d_in[1];
  const float* qkv_w  = (const float*)d_in[2];
  const float* rnet_w = (const float*)d_in[3];
  const float* o_w    = (const float*)d_in[4];
  const float* rrb    = (const float*)d_in[5];  // r_r_bias -> BD
  const float* rwb    = (const float*)d_in[6];  // r_w_bias -> AC

  char* ws = (char*)d_ws;
  size_t off = 0;
  auto alloc = [&](size_t bytes) -> void* {
    void* p = ws + off; off += (bytes + 255) & ~(size_t)255; return p;
  };
  u16* Xbf    = (u16*)alloc((size_t)4096 * 1024 * 2);
  u16* Rbf    = (u16*)alloc((size_t)2048 * 1024 * 2);
  u16* Wqkvt  = (u16*)alloc((size_t)3072 * 1024 * 2);
  u16* Wrt    = (u16*)alloc((size_t)1024 * 1024 * 2);
  u16* Wot    = (u16*)alloc((size_t)1024 * 1024 * 2);
  u16* Qs     = (u16*)alloc((size_t)32 * 2048 * 64 * 2);
  u16* Ks     = (u16*)alloc((size_t)32 * 2048 * 64 * 2);
  u16* Vs     = (u16*)alloc((size_t)32 * 2048 * 64 * 2);
  u16* Vts    = (u16*)alloc((size_t)32 * 64 * 2048 * 2);
  u16* RKs    = (u16*)alloc((size_t)16 * 2048 * 64 * 2);
  float* bias_ac = (float*)alloc((size_t)32 * 2048 * 4);
  float* bias_bd = (float*)alloc((size_t)16 * 2048 * 4);
  float* m_part  = (float*)alloc((size_t)4 * 32 * 2048 * 4);
  float* l_part  = (float*)alloc((size_t)4 * 32 * 2048 * 4);
  float* m_fin   = (float*)alloc((size_t)32 * 2048 * 4);
  float* l_fin   = (float*)alloc((size_t)32 * 2048 * 4);
  float* Ovp     = (float*)alloc((size_t)4 * 4096 * 1024 * 4);
  u16* Ov     = (u16*)alloc((size_t)4096 * 1024 * 2);

  float* out0 = (float*)d_out;
  float* PROB = out0 + 4194304;
  float* ACo  = PROB + 134217728;
  float* BDo  = ACo  + 134217728;

  k_cast<<<dim3(4096), dim3(256), 0, stream>>>(w, Xbf, 1048576);
  k_cast<<<dim3(2048), dim3(256), 0, stream>>>(r, Rbf, 524288);
  k_tc<<<dim3(96, 32), dim3(256), 0, stream>>>(qkv_w,  Wqkvt, 1024, 3072);
  k_tc<<<dim3(32, 32), dim3(256), 0, stream>>>(rnet_w, Wrt,   1024, 1024);
  k_tc<<<dim3(32, 32), dim3(256), 0, stream>>>(o_w,    Wot,   1024, 1024);
  k_gemm<0><<<dim3(32, 12), dim3(512), 0, stream>>>(Xbf, Wqkvt, Qs, Ks, Vs, nullptr, nullptr);
  k_gemm<1><<<dim3(16, 4),  dim3(512), 0, stream>>>(Rbf, Wrt,  RKs, nullptr, nullptr, nullptr, nullptr);
  k_bias<<<dim3(256), dim3(256), 0, stream>>>(Ks,  rwb, bias_ac, 65536);
  k_bias<<<dim3(128), dim3(256), 0, stream>>>(RKs, rrb, bias_bd, 32768);
  k_trv<<<dim3(32, 32), dim3(256), 0, stream>>>(Vs, Vts);
  k_bd<<<dim3(128, 2, 4), dim3(512), 0, stream>>>(Qs, RKs, bias_bd, BDo);
  k_bdiag<<<dim3(256), dim3(256), 0, stream>>>(BDo);
  k_stats<<<dim3(128, 2, 4), dim3(512), 0, stream>>>(Qs, Ks, bias_ac, BDo, ACo, m_part, l_part);
  k_comb<<<dim3(256), dim3(256), 0, stream>>>(m_part, l_part, m_fin, l_fin);
  k_prob_pv<<<dim3(128, 2, 4), dim3(512), 0, stream>>>(Qs, Ks, Vts, bias_ac, BDo, m_fin, l_fin, PROB, Ovp);
  k_ovred<<<dim3(4096), dim3(256), 0, stream>>>(Ovp, Ov);
  k_gemm<2><<<dim3(32, 4), dim3(512), 0, stream>>>(Ov, Wot, nullptr, nullptr, nullptr, w, out0);
}

// Round 5
// 1218.131 us; speedup vs baseline: 1.3248x; 1.0319x over previous
//
#include <hip/hip_runtime.h>
#include <hip/hip_bf16.h>

// Transformer-XL relative multi-head attention, MI355X (gfx950).
// Shapes: QLEN=RLEN=KLEN=2048, BSZ=2, NH=16, DH=64, DM=1024. SCALE=0.125.
// Outputs (f32, concat): out0[2048,2,1024], prob[2048,2048,2,16],
//                        AC[2048,2048,2,16], BD[2048,2048,2,16]
// R5: k_bd/k_bdiag deleted. BD is generated INSIDE k_stats via an
//     incremental diagonal ring (dbuf 32-j LDS windows, per-step only the
//     strictly-new RK c-tiles: ~1.05x redundancy vs R3's 1.75x), flushed
//     to the BD output from LDS. Saves 536MB BD read + the k_bd dispatch.
//     k_prob_pv unchanged from R4 (reads BD from global with prefetch).

typedef unsigned short u16;
typedef __attribute__((ext_vector_type(8))) short short8;   // 8 bf16 (4 VGPR)
typedef __attribute__((ext_vector_type(4))) float f32x4;
typedef __attribute__((ext_vector_type(4))) unsigned short u16x4;

__device__ __forceinline__ u16 f2bf(float x){
  unsigned u = __float_as_uint(x);
  u += 0x7fffu + ((u >> 16) & 1u);          // RNE
  return (u16)(u >> 16);
}
__device__ __forceinline__ float bf2f(u16 s){
  return __uint_as_float(((unsigned)s) << 16);
}
__device__ __forceinline__ f32x4 mfma16(short8 a, short8 b, f32x4 c){
  return __builtin_amdgcn_mfma_f32_16x16x32_bf16(a, b, c, 0, 0, 0);
}
__device__ __forceinline__ void ntst4(float* p, f32x4 v){
  __builtin_nontemporal_store(v, (f32x4*)p);
}

// ---------------- prep: casts / transposes ----------------

__global__ __launch_bounds__(256) void k_cast(const float* __restrict__ src, u16* __restrict__ dst, int n4){
  int i = blockIdx.x * 256 + threadIdx.x;
  if (i >= n4) return;
  f32x4 v = *(const f32x4*)(src + (size_t)i * 4);
  u16x4 o;
  #pragma unroll
  for (int q = 0; q < 4; ++q) o[q] = f2bf(v[q]);
  *(u16x4*)(dst + (size_t)i * 4) = o;
}

// src f32 [R][C] -> dst bf16 [C][R]
__global__ __launch_bounds__(256) void k_tc(const float* __restrict__ src, u16* __restrict__ dst, int R, int C){
  __shared__ float ld[32][33];
  int c0 = blockIdx.x * 32, r0 = blockIdx.y * 32;
  int t = threadIdx.x;
  int r = t >> 3, c4 = (t & 7) * 4;
  f32x4 v = *(const f32x4*)(src + (size_t)(r0 + r) * C + c0 + c4);
  #pragma unroll
  for (int q = 0; q < 4; ++q) ld[r][c4 + q] = v[q];
  __syncthreads();
  int c = t >> 3, r4 = (t & 7) * 4;
  u16x4 o;
  #pragma unroll
  for (int q = 0; q < 4; ++q) o[q] = f2bf(ld[r4 + q][c]);
  *(u16x4*)(dst + (size_t)(c0 + c) * R + r0 + r4) = o;
}

// ---------------- GEMM: C[M,N] = A[M,1024] @ Bt[N,1024]^T ----------------

template<int MODE>
__global__ __launch_bounds__(512) void k_gemm(const u16* __restrict__ A, const u16* __restrict__ Bt,
        u16* __restrict__ o0, u16* __restrict__ o1, u16* __restrict__ o2,
        const float* __restrict__ wres, float* __restrict__ outf)
{
  __shared__ __align__(16) u16 As[128][40];
  __shared__ __align__(16) u16 Bs[256][40];
  const int t = threadIdx.x;
  const int wave = t >> 6, lane = t & 63;
  const int wr = wave >> 2, wc = wave & 3;
  const int g = lane >> 4, li = lane & 15;
  const int m0 = blockIdx.x * 128, n0 = blockIdx.y * 256;
  f32x4 acc[4][4] = {};
  const int ar = t >> 2, ac8 = (t & 3) * 8;
  for (int kt = 0; kt < 32; ++kt){
    int k0 = kt * 32;
    *(short8*)&As[ar][ac8] = *(const short8*)(A + (size_t)(m0 + ar) * 1024 + k0 + ac8);
    #pragma unroll
    for (int u = 0; u < 2; ++u){
      int id = t + 512 * u; int br = id >> 2, bc8 = (id & 3) * 8;
      *(short8*)&Bs[br][bc8] = *(const short8*)(Bt + (size_t)(n0 + br) * 1024 + k0 + bc8);
    }
    __syncthreads();
    short8 af[4], bfv[4];
    #pragma unroll
    for (int mf = 0; mf < 4; ++mf) af[mf] = *(const short8*)&As[wr * 64 + mf * 16 + li][g * 8];
    #pragma unroll
    for (int nf = 0; nf < 4; ++nf) bfv[nf] = *(const short8*)&Bs[wc * 64 + nf * 16 + li][g * 8];
    #pragma unroll
    for (int mf = 0; mf < 4; ++mf)
      #pragma unroll
      for (int nf = 0; nf < 4; ++nf)
        acc[mf][nf] = mfma16(af[mf], bfv[nf], acc[mf][nf]);
    __syncthreads();
  }
  #pragma unroll
  for (int mf = 0; mf < 4; ++mf)
  #pragma unroll
  for (int nf = 0; nf < 4; ++nf)
  #pragma unroll
  for (int r = 0; r < 4; ++r){
    int gr = m0 + wr * 64 + mf * 16 + g * 4 + r;
    int gc = n0 + wc * 64 + nf * 16 + li;
    float v = acc[mf][nf][r];
    if (MODE == 0){
      int part = gc >> 10, hh = gc & 1023;
      int hn = hh >> 6, d = hh & 63;
      int i = gr >> 1, b = gr & 1;
      u16* dst = (part == 0) ? o0 : ((part == 1) ? o1 : o2);
      dst[((((b << 4) + hn) * 2048 + i) << 6) + d] = f2bf(v);
    } else if (MODE == 1){
      int hn = gc >> 6, d = gc & 63;
      o0[((hn * 2048 + gr) << 6) + d] = f2bf(v);
    } else {
      size_t idx = (size_t)gr * 1024 + gc;
      outf[idx] = wres[idx] + v;
    }
  }
}

// bias vectors: out[g][j] = sum_d bv[g&15][d] * Km[g][j][d]
__global__ __launch_bounds__(256) void k_bias(const u16* __restrict__ Km, const float* __restrict__ bv,
                                              float* __restrict__ out, int total){
  int idx = blockIdx.x * 256 + threadIdx.x;
  if (idx >= total) return;
  int n = (idx >> 11) & 15;
  const u16* kr = Km + ((size_t)idx << 6);
  const float* bp = bv + n * 64;
  float s = 0.f;
  #pragma unroll
  for (int d8 = 0; d8 < 8; ++d8){
    short8 v = *(const short8*)(kr + d8 * 8);
    #pragma unroll
    for (int q = 0; q < 8; ++q) s += bp[d8 * 8 + q] * bf2f((u16)v[q]);
  }
  out[idx] = s;
}

// V [bn][j][d] -> Vt [bn][d][j]
__global__ __launch_bounds__(256) void k_trv(const u16* __restrict__ V, u16* __restrict__ Vt){
  __shared__ __align__(16) u16 ld[64][72];
  int bn = blockIdx.x, j0 = blockIdx.y * 64;
  int t = threadIdx.x;
  #pragma unroll
  for (int u = 0; u < 2; ++u){
    int id = t + 256 * u; int r = id >> 3, c8 = (id & 7) * 8;
    *(short8*)&ld[r][c8] = *(const short8*)(V + ((size_t)(bn * 2048 + j0 + r) << 6) + c8);
  }
  __syncthreads();
  #pragma unroll
  for (int u = 0; u < 2; ++u){
    int id = t + 256 * u; int d = id >> 3, j8 = (id & 7) * 8;
    short8 o;
    #pragma unroll
    for (int q = 0; q < 8; ++q) o[q] = ld[j8 + q][d];
    *(short8*)(Vt + ((size_t)(bn * 64 + d) << 11) + j0 + j8) = o;
  }
}

// ---------------- pass 1: fused BD-ring + AC + split-j softmax stats ----------------
// Shifted BD assembled incrementally: per 32-j step compute only the NEW
// aligned RK c-tiles (case1 {m+2048,m+2064} via qa rows i0..i0+15; case2
// {m,m+16} via qb rows i0+1..i0+16; 3-tile backfill at step 0). Elements
// scatter to ring buffer cur (jw<32) or cur^1 (32..63). Window complete at
// consume time; diagonal j=i+1 stays zero from zero-fill.
__global__ __launch_bounds__(512, 4) void k_statsR(const u16* __restrict__ Q, const u16* __restrict__ RK,
        const u16* __restrict__ Kc, const float* __restrict__ bias_ac, const float* __restrict__ bias_bd,
        float* __restrict__ ACo, float* __restrict__ BDo,
        float* __restrict__ m_part, float* __restrict__ l_part)
{
  __shared__ u16 sBD[2][16 * 544];             // [fr][jw][n] strides 544/17
  __shared__ u16 sB[32 * 271];                 // AC out: [j]*271 + n*17 + row
  const int t = threadIdx.x, wave = t >> 6, lane = t & 63;
  const int g = lane >> 4, li = lane & 15;
  const int i0 = blockIdx.x * 16, b = blockIdx.y;
  const int jbase = blockIdx.z * 512;
  short8 qa[2][2], qb[2][2];
  #pragma unroll
  for (int nn = 0; nn < 2; ++nn){
    int bn = b * 16 + wave * 2 + nn;
    const u16* qp = Q + ((size_t)(bn * 2048 + i0 + li) << 6) + g * 8;
    qa[nn][0] = *(const short8*)qp;
    qa[nn][1] = *(const short8*)(qp + 32);
    int rowB = i0 + 1 + li; if (rowB > 2047) rowB = 2047;   // row 2048 never consumed
    const u16* qp2 = Q + ((size_t)(bn * 2048 + rowB) << 6) + g * 8;
    qb[nn][0] = *(const short8*)qp2;
    qb[nn][1] = *(const short8*)(qp2 + 32);
  }
  for (int w2 = t; w2 < 2 * 4352; w2 += 512) ((unsigned*)sBD)[w2] = 0;

  float m_[2][4], l_[2][4];
  #pragma unroll
  for (int nn = 0; nn < 2; ++nn)
    #pragma unroll
    for (int r = 0; r < 4; ++r){ m_[nn][r] = -__builtin_inff(); l_[nn][r] = 0.f; }

  int cur = 0;
  for (int ch = 0; ch < 16; ++ch){
    int j0 = jbase + ch * 32;
    int m = j0 - i0;
    __syncthreads();                           // zeros / prev-phase done
    u16* bufA = &sBD[cur][0];
    u16* bufB = &sBD[cur ^ 1][0];

    auto do_tile = [&](int c0, bool case2){
      if (c0 < 0 || c0 > 2032) return;
      int off = c0 - m + (case2 ? 2 : -2047);
      #pragma unroll
      for (int nn = 0; nn < 2; ++nn){
        int n = wave * 2 + nn;
        const u16* rp = RK + ((size_t)(n * 2048 + c0 + li) << 6) + g * 8;
        short8 b0 = *(const short8*)rp;
        short8 b1 = *(const short8*)(rp + 32);
        f32x4 acc = {};
        acc = mfma16(case2 ? qb[nn][0] : qa[nn][0], b0, acc);
        acc = mfma16(case2 ? qb[nn][1] : qa[nn][1], b1, acc);
        float bb = bias_bd[n * 2048 + c0 + li];
        #pragma unroll
        for (int r = 0; r < 4; ++r){
          int fr = g * 4 + r;
          int jw = li + fr + off;
          u16 val = f2bf(acc[r] + bb);
          if ((unsigned)jw < 32u)       bufA[fr * 544 + jw * 17 + n] = val;
          else if ((unsigned)jw < 64u)  bufB[fr * 544 + (jw - 32) * 17 + n] = val;
        }
      }
    };
    if (ch == 0){                              // backfill (prior steps' share)
      do_tile(m + 2032, false);
      do_tile(m - 32, true);
      do_tile(m - 16, true);
    }
    do_tile(m + 2048, false);
    do_tile(m + 2064, false);
    do_tile(m, true);
    do_tile(m + 16, true);
    __syncthreads();                           // bufA complete for window ch

    #pragma unroll
    for (int nn = 0; nn < 2; ++nn){
      int n = wave * 2 + nn, bn = b * 16 + n;
      float sv[2][4];
      #pragma unroll
      for (int cf = 0; cf < 2; ++cf){
        int jc = j0 + cf * 16 + li;
        const u16* kp = Kc + ((size_t)(bn * 2048 + jc) << 6) + g * 8;
        short8 b0 = *(const short8*)kp;
        short8 b1 = *(const short8*)(kp + 32);
        f32x4 acc = {};
        acc = mfma16(qa[nn][0], b0, acc);
        acc = mfma16(qa[nn][1], b1, acc);
        float ba = bias_ac[bn * 2048 + jc];
        #pragma unroll
        for (int r = 0; r < 4; ++r){
          float av = acc[r] + ba;                               // AC value
          sB[(cf * 16 + li) * 271 + n * 17 + g * 4 + r] = f2bf(av);
          float bd = bf2f(bufA[(g * 4 + r) * 544 + (cf * 16 + li) * 17 + n]);
          sv[cf][r] = (av + bd) * 0.125f;
        }
      }
      float cm[4], mn[4], ps[4];
      #pragma unroll
      for (int r = 0; r < 4; ++r) cm[r] = fmaxf(sv[0][r], sv[1][r]);
      #pragma unroll
      for (int off = 1; off < 16; off <<= 1)
        #pragma unroll
        for (int r = 0; r < 4; ++r) cm[r] = fmaxf(cm[r], __shfl_xor(cm[r], off));
      #pragma unroll
      for (int r = 0; r < 4; ++r){
        mn[r] = fmaxf(m_[nn][r], cm[r]);
        ps[r] = __expf(sv[0][r] - mn[r]) + __expf(sv[1][r] - mn[r]);
      }
      #pragma unroll
      for (int off = 1; off < 16; off <<= 1)
        #pragma unroll
        for (int r = 0; r < 4; ++r) ps[r] += __shfl_xor(ps[r], off);
      #pragma unroll
      for (int r = 0; r < 4; ++r){
        l_[nn][r] = l_[nn][r] * __expf(m_[nn][r] - mn[r]) + ps[r];
        m_[nn][r] = mn[r];
      }
    }
    // BD flush (reads bufA; bufA not written in this phase)
    #pragma unroll
    for (int u = 0; u < 4; ++u){
      int flat4 = t + 512 * u;
      int n4 = (flat4 & 3) * 4, jl = (flat4 >> 2) & 31, row = flat4 >> 7;
      f32x4 v;
      #pragma unroll
      for (int q = 0; q < 4; ++q) v[q] = bf2f(bufA[row * 544 + jl * 17 + n4 + q]);
      ntst4(BDo + (((size_t)(i0 + row) * 2048 + j0 + jl) << 5) + b * 16 + n4, v);
    }
    __syncthreads();                           // sB complete, bufA reads done
    // AC flush + zero bufA (becomes next step's overflow buffer)
    #pragma unroll
    for (int u = 0; u < 4; ++u){
      int flat4 = t + 512 * u;
      int n4 = (flat4 & 3) * 4, jl = (flat4 >> 2) & 31, row = flat4 >> 7;
      f32x4 v;
      #pragma unroll
      for (int q = 0; q < 4; ++q) v[q] = bf2f(sB[jl * 271 + (n4 + q) * 17 + row]);
      ntst4(ACo + (((size_t)(i0 + row) * 2048 + j0 + jl) << 5) + b * 16 + n4, v);
    }
    for (int w2 = t; w2 < 4352; w2 += 512) ((unsigned*)bufA)[w2] = 0;
    cur ^= 1;
  }
  if (li == 0){
    #pragma unroll
    for (int nn = 0; nn < 2; ++nn)
      #pragma unroll
      for (int r = 0; r < 4; ++r){
        int bn = b * 16 + wave * 2 + nn;
        size_t o = ((size_t)(blockIdx.z * 32 + bn)) * 2048 + i0 + g * 4 + r;
        m_part[o] = m_[nn][r];
        l_part[o] = l_[nn][r];
      }
  }
}

// combine split-j stats: m = max, l = sum l_js * exp(m_js - m)
__global__ __launch_bounds__(256) void k_comb(const float* __restrict__ mp, const float* __restrict__ lp,
                                              float* __restrict__ mf, float* __restrict__ lf){
  int idx = blockIdx.x * 256 + threadIdx.x;    // 32*2048 = 65536
  float m = -__builtin_inff();
  #pragma unroll
  for (int js = 0; js < 4; ++js) m = fmaxf(m, mp[js * 65536 + idx]);
  float l = 0.f;
  #pragma unroll
  for (int js = 0; js < 4; ++js) l += lp[js * 65536 + idx] * __expf(mp[js * 65536 + idx] - m);
  mf[idx] = m;
  lf[idx] = l;
}

// ---------------- pass 2: prob write + P.V partials (R4 structure) ----------------
__global__ __launch_bounds__(512, 4) void k_prob_pv(const u16* __restrict__ Q, const u16* __restrict__ Kc,
        const u16* __restrict__ Vt, const float* __restrict__ bias_ac, const float* __restrict__ BD,
        const float* __restrict__ m_f, const float* __restrict__ l_f,
        float* __restrict__ PROB, float* __restrict__ Ovp)
{
  __shared__ __align__(16) u16 sA[16 * 648];
  __shared__ u16 sB[32 * 271];
  const int t = threadIdx.x, wave = t >> 6, lane = t & 63;
  const int g = lane >> 4, li = lane & 15;
  const int i0 = blockIdx.x * 16, b = blockIdx.y;
  const int jbase = blockIdx.z * 512;
  short8 qa[2][2];
  float m_[2][4], rl_[2][4];
  #pragma unroll
  for (int nn = 0; nn < 2; ++nn){
    int bn = b * 16 + wave * 2 + nn;
    const u16* qp = Q + ((size_t)(bn * 2048 + i0 + li) << 6) + g * 8;
    qa[nn][0] = *(const short8*)qp;
    qa[nn][1] = *(const short8*)(qp + 32);
    #pragma unroll
    for (int r = 0; r < 4; ++r){
      m_[nn][r]  = m_f[bn * 2048 + i0 + g * 4 + r];
      rl_[nn][r] = 1.f / l_f[bn * 2048 + i0 + g * 4 + r];
    }
  }
  f32x4 oacc[2][4] = {};

  f32x4 pfv[4];
  #pragma unroll
  for (int u = 0; u < 4; ++u){
    int flat4 = t + 512 * u;
    int n4 = (flat4 & 3) * 4, jl = (flat4 >> 2) & 31, row = flat4 >> 7;
    pfv[u] = *(const f32x4*)(BD + (((size_t)(i0 + row) * 2048 + jbase + jl) << 5) + b * 16 + n4);
  }

  for (int ch = 0; ch < 16; ++ch){
    int j0 = jbase + ch * 32;
    __syncthreads();
    #pragma unroll
    for (int u = 0; u < 4; ++u){
      int flat4 = t + 512 * u;
      int n4 = (flat4 & 3) * 4, jl = (flat4 >> 2) & 31, row = flat4 >> 7;
      u16x4 o;
      #pragma unroll
      for (int q = 0; q < 4; ++q) o[q] = (u16)(__float_as_uint(pfv[u][q]) >> 16);
      *(u16x4*)&sA[row * 648 + jl * 20 + n4] = o;
    }
    if (ch + 1 < 16){
      #pragma unroll
      for (int u = 0; u < 4; ++u){
        int flat4 = t + 512 * u;
        int n4 = (flat4 & 3) * 4, jl = (flat4 >> 2) & 31, row = flat4 >> 7;
        pfv[u] = *(const f32x4*)(BD + (((size_t)(i0 + row) * 2048 + j0 + 32 + jl) << 5) + b * 16 + n4);
      }
    }
    __syncthreads();
    #pragma unroll
    for (int nn = 0; nn < 2; ++nn){
      int n = wave * 2 + nn, bn = b * 16 + n;
      #pragma unroll
      for (int cf = 0; cf < 2; ++cf){
        int jc = j0 + cf * 16 + li;
        const u16* kp = Kc + ((size_t)(bn * 2048 + jc) << 6) + g * 8;
        short8 b0 = *(const short8*)kp;
        short8 b1 = *(const short8*)(kp + 32);
        f32x4 acc = {};
        acc = mfma16(qa[nn][0], b0, acc);
        acc = mfma16(qa[nn][1], b1, acc);
        float ba = bias_ac[bn * 2048 + jc];
        #pragma unroll
        for (int r = 0; r < 4; ++r){
          float bd = bf2f(sA[(g * 4 + r) * 648 + (cf * 16 + li) * 20 + n]);
          float s = (acc[r] + ba + bd) * 0.125f;
          float p = __expf(s - m_[nn][r]) * rl_[nn][r];
          sB[(cf * 16 + li) * 271 + n * 17 + g * 4 + r] = f2bf(p);
        }
      }
    }
    // PV: own-wave repack from sB (A-frag: row=lane&15, k=8*(lane>>4)+tt)
    #pragma unroll
    for (int nn = 0; nn < 2; ++nn){
      int n = wave * 2 + nn, bn = b * 16 + n;
      short8 pa;
      #pragma unroll
      for (int tt = 0; tt < 8; ++tt) pa[tt] = (short)sB[(g * 8 + tt) * 271 + n * 17 + li];
      const u16* vb = Vt + ((size_t)(bn * 64) << 11) + j0 + g * 8;
      #pragma unroll
      for (int vf = 0; vf < 4; ++vf){
        short8 bv = *(const short8*)(vb + ((size_t)(vf * 16 + li) << 11));
        oacc[nn][vf] = mfma16(pa, bv, oacc[nn][vf]);
      }
    }
    __syncthreads();
    #pragma unroll
    for (int u = 0; u < 4; ++u){
      int flat4 = t + 512 * u;
      int n4 = (flat4 & 3) * 4, jl = (flat4 >> 2) & 31, row = flat4 >> 7;
      f32x4 v;
      #pragma unroll
      for (int q = 0; q < 4; ++q) v[q] = bf2f(sB[jl * 271 + (n4 + q) * 17 + row]);
      ntst4(PROB + (((size_t)(i0 + row) * 2048 + j0 + jl) << 5) + b * 16 + n4, v);
    }
  }
  float* op = Ovp + (size_t)blockIdx.z * 4194304;
  #pragma unroll
  for (int nn = 0; nn < 2; ++nn){
    int n = wave * 2 + nn;
    #pragma unroll
    for (int vf = 0; vf < 4; ++vf)
      #pragma unroll
      for (int r = 0; r < 4; ++r)
        op[(size_t)((i0 + g * 4 + r) * 2 + b) * 1024 + n * 64 + vf * 16 + li] = oacc[nn][vf][r];
  }
}

// reduce 4 PV partials -> bf16 attn_vec
__global__ __launch_bounds__(256) void k_ovred(const float* __restrict__ ovp, u16* __restrict__ ov){
  int i = blockIdx.x * 256 + threadIdx.x;      // over 1048576 f32x4 groups
  const f32x4* p = (const f32x4*)ovp;
  f32x4 s = p[i];
  #pragma unroll
  for (int js = 1; js < 4; ++js) s += p[(size_t)js * 1048576 + i];
  u16x4 o;
  #pragma unroll
  for (int q = 0; q < 4; ++q) o[q] = f2bf(s[q]);
  ((u16x4*)ov)[i] = o;
}

// ---------------- launch ----------------

extern "C" void kernel_launch(void* const* d_in, const int* in_sizes, int n_in,
                              void* d_out, int out_size, void* d_ws, size_t ws_size,
                              hipStream_t stream)
{
  const float* w      = (const float*)d_in[0];
  const float* r      = (const float*)d_in[1];
  const float* qkv_w  = (const float*)d_in[2];
  const float* rnet_w = (const float*)d_in[3];
  const float* o_w    = (const float*)d_in[4];
  const float* rrb    = (const float*)d_in[5];  // r_r_bias -> BD
  const float* rwb    = (const float*)d_in[6];  // r_w_bias -> AC

  char* ws = (char*)d_ws;
  size_t off = 0;
  auto alloc = [&](size_t bytes) -> void* {
    void* p = ws + off; off += (bytes + 255) & ~(size_t)255; return p;
  };
  u16* Xbf    = (u16*)alloc((size_t)4096 * 1024 * 2);
  u16* Rbf    = (u16*)alloc((size_t)2048 * 1024 * 2);
  u16* Wqkvt  = (u16*)alloc((size_t)3072 * 1024 * 2);
  u16* Wrt    = (u16*)alloc((size_t)1024 * 1024 * 2);
  u16* Wot    = (u16*)alloc((size_t)1024 * 1024 * 2);
  u16* Qs     = (u16*)alloc((size_t)32 * 2048 * 64 * 2);
  u16* Ks     = (u16*)alloc((size_t)32 * 2048 * 64 * 2);
  u16* Vs     = (u16*)alloc((size_t)32 * 2048 * 64 * 2);
  u16* Vts    = (u16*)alloc((size_t)32 * 64 * 2048 * 2);
  u16* RKs    = (u16*)alloc((size_t)16 * 2048 * 64 * 2);
  float* bias_ac = (float*)alloc((size_t)32 * 2048 * 4);
  float* bias_bd = (float*)alloc((size_t)16 * 2048 * 4);
  float* m_part  = (float*)alloc((size_t)4 * 32 * 2048 * 4);
  float* l_part  = (float*)alloc((size_t)4 * 32 * 2048 * 4);
  float* m_fin   = (float*)alloc((size_t)32 * 2048 * 4);
  float* l_fin   = (float*)alloc((size_t)32 * 2048 * 4);
  float* Ovp     = (float*)alloc((size_t)4 * 4096 * 1024 * 4);
  u16* Ov     = (u16*)alloc((size_t)4096 * 1024 * 2);

  float* out0 = (float*)d_out;
  float* PROB = out0 + 4194304;
  float* ACo  = PROB + 134217728;
  float* BDo  = ACo  + 134217728;

  k_cast<<<dim3(4096), dim3(256), 0, stream>>>(w, Xbf, 1048576);
  k_cast<<<dim3(2048), dim3(256), 0, stream>>>(r, Rbf, 524288);
  k_tc<<<dim3(96, 32), dim3(256), 0, stream>>>(qkv_w,  Wqkvt, 1024, 3072);
  k_tc<<<dim3(32, 32), dim3(256), 0, stream>>>(rnet_w, Wrt,   1024, 1024);
  k_tc<<<dim3(32, 32), dim3(256), 0, stream>>>(o_w,    Wot,   1024, 1024);
  k_gemm<0><<<dim3(32, 12), dim3(512), 0, stream>>>(Xbf, Wqkvt, Qs, Ks, Vs, nullptr, nullptr);
  k_gemm<1><<<dim3(16, 4),  dim3(512), 0, stream>>>(Rbf, Wrt,  RKs, nullptr, nullptr, nullptr, nullptr);
  k_bias<<<dim3(256), dim3(256), 0, stream>>>(Ks,  rwb, bias_ac, 65536);
  k_bias<<<dim3(128), dim3(256), 0, stream>>>(RKs, rrb, bias_bd, 32768);
  k_trv<<<dim3(32, 32), dim3(256), 0, stream>>>(Vs, Vts);
  k_statsR<<<dim3(128, 2, 4), dim3(512), 0, stream>>>(Qs, RKs, Ks, bias_ac, bias_bd, ACo, BDo, m_part, l_part);
  k_comb<<<dim3(256), dim3(256), 0, stream>>>(m_part, l_part, m_fin, l_fin);
  k_prob_pv<<<dim3(128, 2, 4), dim3(512), 0, stream>>>(Qs, Ks, Vts, bias_ac, BDo, m_fin, l_fin, PROB, Ovp);
  k_ovred<<<dim3(4096), dim3(256), 0, stream>>>(Ovp, Ov);
  k_gemm<2><<<dim3(32, 4), dim3(512), 0, stream>>>(Ov, Wot, nullptr, nullptr, nullptr, w, out0);
}